// Round 14
// baseline (120.642 us; speedup 1.0000x reference)
//
#include <hip/hip_runtime.h>

#define HW_TOTAL (4096 * 4096)
#define NBINS 256
#define NCHUNK (HW_TOTAL / 4)      // int4 chunks = 4M
#define NSUB 16                    // LDS sub-histograms

#define HGRID 512                  // hist blocks (px/block = 32768 -> u16-safe)
#define HCPT 8                     // int4 chunks per thread
// 512 * 1024 * 8 = 4M exactly.

#define BGRID 512                  // bin blocks
#define BUPT 2                     // uint4 packed loads per thread (32 px)
// 512 * 1024 * 2 uint4 * 16 px = 16.7M px exactly.

#define BLK 1024

typedef int int4n __attribute__((ext_vector_type(4)));               // aligned 16
typedef int int4a __attribute__((ext_vector_type(4), aligned(4)));   // dword-aligned

// ws layout: [0] thresh (u32); +256 B: partials u16[HGRID][NBINS] (256 KB);
// +256 B + 256 KB: packed u8 image (16 MB, as u32[NCHUNK]).
#define WS_PART_OFF 256
#define WS_PACK_OFF (256 + HGRID * NBINS * 2)
#define WS_NEED (WS_PACK_OFF + NCHUNK * 4)

// ---------------------------------------------------------------------------
// Otsu threshold from a 256-bin count histogram in LDS, one wave (lane = t).
// Exact uint64 prefix scan via shfl + fp64 inter-class variance argmax
// (val_sum[t] == t*cnt[t] exactly, so only the count histogram is needed).
// ---------------------------------------------------------------------------
__device__ __forceinline__ int otsu_scan64(const unsigned* cnt, int lane) {
    uint4 c4 = ((const uint4*)cnt)[lane];
    unsigned cs[4] = {c4.x, c4.y, c4.z, c4.w};

    unsigned long long lc[4], lv[4];
    unsigned long long ccum = 0ull, vcum = 0ull;
#pragma unroll
    for (int k = 0; k < 4; ++k) {
        ccum += cs[k];
        vcum += (unsigned long long)cs[k] * (unsigned)(4 * lane + k);
        lc[k] = ccum;
        lv[k] = vcum;
    }
    unsigned long long cscan = ccum, vscan = vcum;
    for (int d = 1; d < 64; d <<= 1) {
        unsigned long long cu = __shfl_up(cscan, d);
        unsigned long long vu = __shfl_up(vscan, d);
        if (lane >= d) { cscan += cu; vscan += vu; }
    }
    const unsigned long long cbase = cscan - ccum;
    const unsigned long long vbase = vscan - vcum;
    const unsigned long long vtotal = __shfl(vscan, 63);

    double best = -1.0;
    int bestt = 255;
    const double hw = (double)HW_TOTAL;
    const double vtot_d = (double)vtotal;
#pragma unroll
    for (int k = 0; k < 4; ++k) {
        int tt = 4 * lane + k;
        if (tt > 254) continue;
        double nb = (double)(cbase + lc[k]);
        double sb = (double)(vbase + lv[k]);
        double nw = hw - nb;
        double sw = vtot_d - sb;
        double dm = sb / nb - sw / nw;
        double var = nb * nw * dm * dm;
        if (var > best || (var == best && tt < bestt)) { best = var; bestt = tt; }
    }
    for (int d = 32; d >= 1; d >>= 1) {
        double ov = __shfl_xor(best, d);
        int ot = __shfl_xor(bestt, d);
        if (ov > best || (ov == best && ot < bestt)) { best = ov; bestt = ot; }
    }
    return bestt;
}

// ---------------------------------------------------------------------------
// Kernel 1: histogram + pack. 16 LDS sub-hists h[sub*256+bin] (bank = bin
// mod 32 -> all banks, ~2-way free). While the pixels are in registers,
// pack 4 px -> u32 and store the byte image (16 MB, cached — bin re-reads
// it instead of the 64 MB int32 img). Flush: one u16 partial row per block.
// MODE 1: u32 global atomic fallback (no packing; bin then reads img).
// ---------------------------------------------------------------------------
template <int MODE>
__global__ __launch_bounds__(BLK, 8) void otsu_hist_k(const int4* __restrict__ img4,
                                                      unsigned short* __restrict__ pout,
                                                      unsigned* __restrict__ packed,
                                                      unsigned* __restrict__ ghist) {
    __shared__ unsigned h[NSUB * NBINS];    // 16 KiB
    const int t = threadIdx.x;
    for (int i = t; i < NSUB * NBINS; i += BLK) h[i] = 0;
    __syncthreads();

    unsigned* hp = h + ((t & (NSUB - 1)) << 8);
    const int wave = t >> 6, lane = t & 63;
    const int i0 = blockIdx.x * (BLK * HCPT) + wave * (64 * HCPT) + lane;

    int4 v[HCPT];
#pragma unroll
    for (int k = 0; k < HCPT; ++k) v[k] = img4[i0 + k * 64];
#pragma unroll
    for (int k = 0; k < HCPT; ++k) {
        if (MODE == 0) {
            unsigned pb = (unsigned)v[k].x | ((unsigned)v[k].y << 8) |
                          ((unsigned)v[k].z << 16) | ((unsigned)v[k].w << 24);
            packed[i0 + k * 64] = pb;
        }
        atomicAdd(&hp[(unsigned)v[k].x], 1u);
        atomicAdd(&hp[(unsigned)v[k].y], 1u);
        atomicAdd(&hp[(unsigned)v[k].z], 1u);
        atomicAdd(&hp[(unsigned)v[k].w], 1u);
    }
    __syncthreads();

    if (t < NBINS) {
        unsigned s = 0;
#pragma unroll
        for (int ss = 0; ss < NSUB; ++ss) s += h[(ss << 8) | t];
        if (MODE == 0) {
            pout[blockIdx.x * NBINS + t] = (unsigned short)s;
        } else {
            if (s) atomicAdd(&ghist[t], s);
        }
    }
}

// ---------------------------------------------------------------------------
// Kernel 2: threshold. One block, 1024 threads. Vectorized reduce of the
// u16 partials table (512 rows x 256 bins = 256 KB) via uint4 loads:
// thread (octet o = t&31, rowgroup g = t>>5) sums 16 rows of its 8-bin
// octet (16 uint4 loads in flight), unpacking u16 pairs into 8 u32 accums.
// LDS reduce across 32 rowgroups, then wave-0 exact scan + fp64 argmax.
// ---------------------------------------------------------------------------
__global__ __launch_bounds__(BLK) void otsu_thresh_k(const unsigned short* __restrict__ partials,
                                                     int* __restrict__ d_out,
                                                     unsigned* __restrict__ thr_ws) {
    __shared__ unsigned red[32][NBINS];    // 32 KiB
    __shared__ unsigned cnt[NBINS];

    const int t = threadIdx.x;
    const int o = t & 31;                  // bin octet: bins 8o..8o+7
    const int g = t >> 5;                  // rowgroup: rows 16g..16g+15
    const uint4* p4 = (const uint4*)partials;   // 32 uint4 per row

    unsigned a0 = 0, a1 = 0, a2 = 0, a3 = 0, a4 = 0, a5 = 0, a6 = 0, a7 = 0;
    uint4 q[16];
#pragma unroll
    for (int j = 0; j < 16; ++j) q[j] = p4[(g * 16 + j) * 32 + o];
#pragma unroll
    for (int j = 0; j < 16; ++j) {
        a0 += q[j].x & 0xFFFFu; a1 += q[j].x >> 16;
        a2 += q[j].y & 0xFFFFu; a3 += q[j].y >> 16;
        a4 += q[j].z & 0xFFFFu; a5 += q[j].z >> 16;
        a6 += q[j].w & 0xFFFFu; a7 += q[j].w >> 16;
    }
    red[g][8 * o + 0] = a0; red[g][8 * o + 1] = a1;
    red[g][8 * o + 2] = a2; red[g][8 * o + 3] = a3;
    red[g][8 * o + 4] = a4; red[g][8 * o + 5] = a5;
    red[g][8 * o + 6] = a6; red[g][8 * o + 7] = a7;
    __syncthreads();

    if (t < NBINS) {
        unsigned s = 0;
#pragma unroll
        for (int gg = 0; gg < 32; ++gg) s += red[gg][t];
        cnt[t] = s;
    }
    __syncthreads();

    if (t < 64) {
        int bt = otsu_scan64(cnt, t);
        if (t == 0) {
            d_out[0] = bt;
            *thr_ws = (unsigned)bt;
        }
    }
}

// ---------------------------------------------------------------------------
// Kernel 3: binarize from the PACKED byte image (16 MB read vs 64 MB).
// Thread loads uint4 = 16 px. Output image lives at out[1..HW]: the +1 shift
// is a byte funnel: w0=(P.x<<8)|prev, w1=(P.y<<8)|(P.x>>24), ... where prev
// (px 16u-1) is the previous lane's P.w top byte via shfl_up (lane-contiguous
// u mapping), lane 0 loads one scalar word. Each w unpacks to 4 output ints
// ((b<=thr)?0:256); 4 x 16 B-aligned nt stores per uint4.
// ---------------------------------------------------------------------------
__global__ __launch_bounds__(BLK, 8) void otsu_bin_k(const unsigned* __restrict__ packed,
                                                     int* __restrict__ out,
                                                     const unsigned* __restrict__ thr_ws) {
    const int thresh = (int)*thr_ws;       // uniform
    const int t = threadIdx.x;
    const int wave = t >> 6, lane = t & 63;
    const int i0 = blockIdx.x * (BLK * BUPT) + wave * (64 * BUPT) + lane;
    const uint4* pk4 = (const uint4*)packed;
    int4n* out4 = (int4n*)out;

#pragma unroll
    for (int k = 0; k < BUPT; ++k) {
        const int u = i0 + k * 64;                 // uint4 index: px 16u..16u+15
        uint4 P = pk4[u];
        unsigned pw = __shfl_up(P.w, 1);           // prev lane's top word
        if (lane == 0) pw = (u > 0) ? packed[4 * u - 1] : 0u;
        const unsigned prev = pw >> 24;            // px 16u-1

        unsigned w[4];
        w[0] = (P.x << 8) | prev;
        w[1] = (P.y << 8) | (P.x >> 24);
        w[2] = (P.z << 8) | (P.y >> 24);
        w[3] = (P.w << 8) | (P.z >> 24);

#pragma unroll
        for (int j = 0; j < 4; ++j) {
            int4n o;
            o.x = ((int)(w[j] & 0xFFu) <= thresh) ? 0 : 256;
            o.y = ((int)((w[j] >> 8) & 0xFFu) <= thresh) ? 0 : 256;
            o.z = ((int)((w[j] >> 16) & 0xFFu) <= thresh) ? 0 : 256;
            o.w = ((int)(w[j] >> 24) <= thresh) ? 0 : 256;
            if (u == 0 && j == 0) o.x = thresh;    // out[0] = threshold
            __builtin_nontemporal_store(o, out4 + 4 * u + j);
        }
    }
    if (i0 == 0)
        out[HW_TOTAL] = ((int)(packed[NCHUNK - 1] >> 24) <= thresh) ? 0 : 256;
}

// ---------------------------------------------------------------------------
// Fallback bin (ws too small): direct img read, ghist scan in prologue.
// ---------------------------------------------------------------------------
__global__ __launch_bounds__(BLK, 8) void otsu_bin_fb_k(const int* __restrict__ img,
                                                        int* __restrict__ out,
                                                        const unsigned* __restrict__ ghist) {
    __shared__ unsigned cnt[NBINS];
    __shared__ int s_thresh;
    const int t = threadIdx.x;
    if (t < NBINS) cnt[t] = ghist[t];
    __syncthreads();
    if (t < 64) {
        int bt = otsu_scan64(cnt, t);
        if (t == 0) s_thresh = bt;
    }
    __syncthreads();
    const int thresh = s_thresh;

    const int wave = t >> 6, lane = t & 63;
    const int i0 = blockIdx.x * (BLK * 8) + wave * (64 * 8) + lane;
#pragma unroll
    for (int k = 0; k < 8; ++k) {
        const int c = i0 + k * 64;
        int4a v = *(const int4a*)(img + (c ? 4 * c - 1 : 0));
        int4n o;
        o.x = (v.x <= thresh) ? 0 : 256;
        o.y = (v.y <= thresh) ? 0 : 256;
        o.z = (v.z <= thresh) ? 0 : 256;
        o.w = (v.w <= thresh) ? 0 : 256;
        if (c == 0) { o.w = o.z; o.z = o.y; o.y = o.x; o.x = thresh; }
        __builtin_nontemporal_store(o, (int4n*)out + c);
    }
    if (i0 == 0)
        out[HW_TOTAL] = (img[HW_TOTAL - 1] <= thresh) ? 0 : 256;
}

extern "C" void kernel_launch(void* const* d_in, const int* in_sizes, int n_in,
                              void* d_out, int out_size, void* d_ws, size_t ws_size,
                              hipStream_t stream) {
    const int* img = (const int*)d_in[0];
    int* out = (int*)d_out;
    unsigned* thr_ws = (unsigned*)d_ws;
    unsigned short* part16 = (unsigned short*)((char*)d_ws + WS_PART_OFF);
    unsigned* packed = (unsigned*)((char*)d_ws + WS_PACK_OFF);
    unsigned* ghist = (unsigned*)((char*)d_ws + WS_PART_OFF);

    if (ws_size >= (size_t)WS_NEED) {
        // 3-node path: hist+pack -> thresh -> bin(packed). No atomics/memsets.
        otsu_hist_k<0><<<HGRID, BLK, 0, stream>>>((const int4*)img, part16, packed, nullptr);
        otsu_thresh_k<<<1, BLK, 0, stream>>>(part16, out, thr_ws);
        otsu_bin_k<<<BGRID, BLK, 0, stream>>>(packed, out, thr_ws);
    } else {
        // fallback: atomic flush into a single u32 256-bin histogram
        (void)hipMemsetAsync(ghist, 0, NBINS * sizeof(unsigned), stream);
        otsu_hist_k<1><<<HGRID, BLK, 0, stream>>>((const int4*)img, nullptr, nullptr, ghist);
        otsu_bin_fb_k<<<BGRID, BLK, 0, stream>>>(img, out, ghist);
    }
}

// Round 15
// 39.704 us; speedup vs baseline: 3.0385x; 3.0385x over previous
//
#include <hip/hip_runtime.h>

#define HW_TOTAL (4096 * 4096)
#define NBINS 256
#define NCHUNK (HW_TOTAL / 4)      // u32/int4 chunks = 4M
#define NSUB 16                    // LDS sub-histograms

#define HGRID 512                  // hist blocks (px/block = 32768 -> u16-safe)
#define HCPT 8                     // int4 chunks per thread
// 512 * 1024 * 8 = 4M exactly.

#define BGRID 512                  // bin blocks
#define BBATCH 8                   // u32 chunks per thread (4 px each)
// 512 * 1024 * 8 = 4M exactly.

#define BLK 1024

typedef int int4n __attribute__((ext_vector_type(4)));               // aligned 16
typedef int int4a __attribute__((ext_vector_type(4), aligned(4)));   // dword-aligned

// ws layout: [0] thresh (u32); +256 B: partials u16[HGRID][NBINS] (256 KB);
// +256 B + 256 KB: packed u8 image (16 MB, as u32[NCHUNK]).
#define WS_PART_OFF 256
#define WS_PACK_OFF (256 + HGRID * NBINS * 2)
#define WS_NEED (WS_PACK_OFF + NCHUNK * 4)

// ---------------------------------------------------------------------------
// Otsu threshold from a 256-bin count histogram in LDS, one wave (lane = t).
// Exact uint64 prefix scan via shfl + fp64 inter-class variance argmax
// (val_sum[t] == t*cnt[t] exactly, so only the count histogram is needed).
// ---------------------------------------------------------------------------
__device__ __forceinline__ int otsu_scan64(const unsigned* cnt, int lane) {
    uint4 c4 = ((const uint4*)cnt)[lane];
    unsigned cs[4] = {c4.x, c4.y, c4.z, c4.w};

    unsigned long long lc[4], lv[4];
    unsigned long long ccum = 0ull, vcum = 0ull;
#pragma unroll
    for (int k = 0; k < 4; ++k) {
        ccum += cs[k];
        vcum += (unsigned long long)cs[k] * (unsigned)(4 * lane + k);
        lc[k] = ccum;
        lv[k] = vcum;
    }
    unsigned long long cscan = ccum, vscan = vcum;
    for (int d = 1; d < 64; d <<= 1) {
        unsigned long long cu = __shfl_up(cscan, d);
        unsigned long long vu = __shfl_up(vscan, d);
        if (lane >= d) { cscan += cu; vscan += vu; }
    }
    const unsigned long long cbase = cscan - ccum;
    const unsigned long long vbase = vscan - vcum;
    const unsigned long long vtotal = __shfl(vscan, 63);

    double best = -1.0;
    int bestt = 255;
    const double hw = (double)HW_TOTAL;
    const double vtot_d = (double)vtotal;
#pragma unroll
    for (int k = 0; k < 4; ++k) {
        int tt = 4 * lane + k;
        if (tt > 254) continue;
        double nb = (double)(cbase + lc[k]);
        double sb = (double)(vbase + lv[k]);
        double nw = hw - nb;
        double sw = vtot_d - sb;
        double dm = sb / nb - sw / nw;
        double var = nb * nw * dm * dm;
        if (var > best || (var == best && tt < bestt)) { best = var; bestt = tt; }
    }
    for (int d = 32; d >= 1; d >>= 1) {
        double ov = __shfl_xor(best, d);
        int ot = __shfl_xor(bestt, d);
        if (ov > best || (ov == best && ot < bestt)) { best = ov; bestt = ot; }
    }
    return bestt;
}

// ---------------------------------------------------------------------------
// Kernel 1 (unchanged from R14): histogram + pack. 16 LDS sub-hists
// h[sub*256+bin]. While pixels are in registers, pack 4 px -> u32 and store
// the byte image (16 MB, cached; bin re-reads it instead of the 64 MB img).
// Flush: one u16 partial row per block. MODE 1: u32 atomic fallback.
// ---------------------------------------------------------------------------
template <int MODE>
__global__ __launch_bounds__(BLK, 8) void otsu_hist_k(const int4* __restrict__ img4,
                                                      unsigned short* __restrict__ pout,
                                                      unsigned* __restrict__ packed,
                                                      unsigned* __restrict__ ghist) {
    __shared__ unsigned h[NSUB * NBINS];    // 16 KiB
    const int t = threadIdx.x;
    for (int i = t; i < NSUB * NBINS; i += BLK) h[i] = 0;
    __syncthreads();

    unsigned* hp = h + ((t & (NSUB - 1)) << 8);
    const int wave = t >> 6, lane = t & 63;
    const int i0 = blockIdx.x * (BLK * HCPT) + wave * (64 * HCPT) + lane;

    int4 v[HCPT];
#pragma unroll
    for (int k = 0; k < HCPT; ++k) v[k] = img4[i0 + k * 64];
#pragma unroll
    for (int k = 0; k < HCPT; ++k) {
        if (MODE == 0) {
            unsigned pb = (unsigned)v[k].x | ((unsigned)v[k].y << 8) |
                          ((unsigned)v[k].z << 16) | ((unsigned)v[k].w << 24);
            packed[i0 + k * 64] = pb;
        }
        atomicAdd(&hp[(unsigned)v[k].x], 1u);
        atomicAdd(&hp[(unsigned)v[k].y], 1u);
        atomicAdd(&hp[(unsigned)v[k].z], 1u);
        atomicAdd(&hp[(unsigned)v[k].w], 1u);
    }
    __syncthreads();

    if (t < NBINS) {
        unsigned s = 0;
#pragma unroll
        for (int ss = 0; ss < NSUB; ++ss) s += h[(ss << 8) | t];
        if (MODE == 0) {
            pout[blockIdx.x * NBINS + t] = (unsigned short)s;
        } else {
            if (s) atomicAdd(&ghist[t], s);
        }
    }
}

// ---------------------------------------------------------------------------
// Kernel 2 (unchanged from R14): threshold. One block; uint4-vectorized
// reduce of the u16 partials (thread (octet,rowgroup) sums 16 rows of its
// 8-bin octet), LDS reduce, wave-0 exact scan + fp64 argmax.
// ---------------------------------------------------------------------------
__global__ __launch_bounds__(BLK) void otsu_thresh_k(const unsigned short* __restrict__ partials,
                                                     int* __restrict__ d_out,
                                                     unsigned* __restrict__ thr_ws) {
    __shared__ unsigned red[32][NBINS];    // 32 KiB
    __shared__ unsigned cnt[NBINS];

    const int t = threadIdx.x;
    const int o = t & 31;                  // bin octet: bins 8o..8o+7
    const int g = t >> 5;                  // rowgroup: rows 16g..16g+15
    const uint4* p4 = (const uint4*)partials;   // 32 uint4 per row

    unsigned a0 = 0, a1 = 0, a2 = 0, a3 = 0, a4 = 0, a5 = 0, a6 = 0, a7 = 0;
    uint4 q[16];
#pragma unroll
    for (int j = 0; j < 16; ++j) q[j] = p4[(g * 16 + j) * 32 + o];
#pragma unroll
    for (int j = 0; j < 16; ++j) {
        a0 += q[j].x & 0xFFFFu; a1 += q[j].x >> 16;
        a2 += q[j].y & 0xFFFFu; a3 += q[j].y >> 16;
        a4 += q[j].z & 0xFFFFu; a5 += q[j].z >> 16;
        a6 += q[j].w & 0xFFFFu; a7 += q[j].w >> 16;
    }
    red[g][8 * o + 0] = a0; red[g][8 * o + 1] = a1;
    red[g][8 * o + 2] = a2; red[g][8 * o + 3] = a3;
    red[g][8 * o + 4] = a4; red[g][8 * o + 5] = a5;
    red[g][8 * o + 6] = a6; red[g][8 * o + 7] = a7;
    __syncthreads();

    if (t < NBINS) {
        unsigned s = 0;
#pragma unroll
        for (int gg = 0; gg < 32; ++gg) s += red[gg][t];
        cnt[t] = s;
    }
    __syncthreads();

    if (t < 64) {
        int bt = otsu_scan64(cnt, t);
        if (t == 0) {
            d_out[0] = bt;
            *thr_ws = (unsigned)bt;
        }
    }
}

// ---------------------------------------------------------------------------
// Kernel 3: binarize from the packed byte image — COALESCED stores.
// One u32 chunk (4 px) per thread per iter: wave reads 256 B contiguous
// (L2/L3-hit) and writes one int4n per lane = 1 KiB contiguous nt-store.
// Out image lives at out[1..HW]: out4[c] = bin of px {4c-1, 4c, 4c+1, 4c+2};
// px 4c-1 is the top byte of packed[c-1] = prev lane's chunk via shfl_up
// (lane 0: one scalar load). Chunk 0 writes out[0] = thresh.
// ---------------------------------------------------------------------------
__global__ __launch_bounds__(BLK, 8) void otsu_bin_k(const unsigned* __restrict__ packed,
                                                     int* __restrict__ out,
                                                     const unsigned* __restrict__ thr_ws) {
    const int thresh = (int)*thr_ws;       // uniform
    const int t = threadIdx.x;
    const int wave = t >> 6, lane = t & 63;
    const int i0 = blockIdx.x * (BLK * BBATCH) + wave * (64 * BBATCH) + lane;
    int4n* out4 = (int4n*)out;

#pragma unroll
    for (int k = 0; k < BBATCH; ++k) {
        const int c = i0 + k * 64;                 // u32 chunk: px 4c..4c+3
        unsigned P = packed[c];
        unsigned pw = __shfl_up(P, 1);             // prev lane's chunk
        if (lane == 0) pw = (c > 0) ? packed[c - 1] : 0u;

        int4n o;
        o.x = ((int)(pw >> 24) <= thresh) ? 0 : 256;         // px 4c-1
        o.y = ((int)(P & 0xFFu) <= thresh) ? 0 : 256;        // px 4c
        o.z = ((int)((P >> 8) & 0xFFu) <= thresh) ? 0 : 256; // px 4c+1
        o.w = ((int)((P >> 16) & 0xFFu) <= thresh) ? 0 : 256;// px 4c+2
        if (c == 0) o.x = thresh;                  // out[0] = threshold
        __builtin_nontemporal_store(o, out4 + c);
    }
    if (i0 == 0)
        out[HW_TOTAL] = ((int)(packed[NCHUNK - 1] >> 24) <= thresh) ? 0 : 256;
}

// ---------------------------------------------------------------------------
// Fallback bin (ws too small): direct img read, ghist scan in prologue.
// ---------------------------------------------------------------------------
__global__ __launch_bounds__(BLK, 8) void otsu_bin_fb_k(const int* __restrict__ img,
                                                        int* __restrict__ out,
                                                        const unsigned* __restrict__ ghist) {
    __shared__ unsigned cnt[NBINS];
    __shared__ int s_thresh;
    const int t = threadIdx.x;
    if (t < NBINS) cnt[t] = ghist[t];
    __syncthreads();
    if (t < 64) {
        int bt = otsu_scan64(cnt, t);
        if (t == 0) s_thresh = bt;
    }
    __syncthreads();
    const int thresh = s_thresh;

    const int wave = t >> 6, lane = t & 63;
    const int i0 = blockIdx.x * (BLK * 8) + wave * (64 * 8) + lane;
#pragma unroll
    for (int k = 0; k < 8; ++k) {
        const int c = i0 + k * 64;
        int4a v = *(const int4a*)(img + (c ? 4 * c - 1 : 0));
        int4n o;
        o.x = (v.x <= thresh) ? 0 : 256;
        o.y = (v.y <= thresh) ? 0 : 256;
        o.z = (v.z <= thresh) ? 0 : 256;
        o.w = (v.w <= thresh) ? 0 : 256;
        if (c == 0) { o.w = o.z; o.z = o.y; o.y = o.x; o.x = thresh; }
        __builtin_nontemporal_store(o, (int4n*)out + c);
    }
    if (i0 == 0)
        out[HW_TOTAL] = (img[HW_TOTAL - 1] <= thresh) ? 0 : 256;
}

extern "C" void kernel_launch(void* const* d_in, const int* in_sizes, int n_in,
                              void* d_out, int out_size, void* d_ws, size_t ws_size,
                              hipStream_t stream) {
    const int* img = (const int*)d_in[0];
    int* out = (int*)d_out;
    unsigned* thr_ws = (unsigned*)d_ws;
    unsigned short* part16 = (unsigned short*)((char*)d_ws + WS_PART_OFF);
    unsigned* packed = (unsigned*)((char*)d_ws + WS_PACK_OFF);
    unsigned* ghist = (unsigned*)((char*)d_ws + WS_PART_OFF);

    if (ws_size >= (size_t)WS_NEED) {
        // 3-node path: hist+pack -> thresh -> bin(packed). No atomics/memsets.
        otsu_hist_k<0><<<HGRID, BLK, 0, stream>>>((const int4*)img, part16, packed, nullptr);
        otsu_thresh_k<<<1, BLK, 0, stream>>>(part16, out, thr_ws);
        otsu_bin_k<<<BGRID, BLK, 0, stream>>>(packed, out, thr_ws);
    } else {
        // fallback: atomic flush into a single u32 256-bin histogram
        (void)hipMemsetAsync(ghist, 0, NBINS * sizeof(unsigned), stream);
        otsu_hist_k<1><<<HGRID, BLK, 0, stream>>>((const int4*)img, nullptr, nullptr, ghist);
        otsu_bin_fb_k<<<BGRID, BLK, 0, stream>>>(img, out, ghist);
    }
}

// Round 16
// 39.494 us; speedup vs baseline: 3.0547x; 1.0053x over previous
//
#include <hip/hip_runtime.h>

#define HW_TOTAL (4096 * 4096)
#define NBINS 256
#define NCHUNK (HW_TOTAL / 4)      // u32/int4 chunks = 4M
#define NSUB 16                    // LDS sub-histograms

#define HGRID 512                  // hist blocks (px/block = 32768 -> u16-safe)
#define HCPT 8                     // int4 chunks per thread
// 512 * 1024 * 8 = 4M exactly.

#define BGRID 512                  // bin blocks
#define BBATCH 8                   // u32 chunks per thread (4 px each)
// 512 * 1024 * 8 = 4M exactly.

#define BLK 1024

typedef int int4n __attribute__((ext_vector_type(4)));               // aligned 16
typedef int int4a __attribute__((ext_vector_type(4), aligned(4)));   // dword-aligned

// ws layout: [0] thresh (u32); +256 B: partials u16[HGRID][NBINS] (256 KB);
// +256 B + 256 KB: packed u8 image (16 MB, as u32[NCHUNK]).
#define WS_PART_OFF 256
#define WS_PACK_OFF (256 + HGRID * NBINS * 2)
#define WS_NEED (WS_PACK_OFF + NCHUNK * 4)

// ---------------------------------------------------------------------------
// Otsu threshold from a 256-bin count histogram in LDS, one wave (lane = t).
// Exact uint64 prefix scan via shfl + fp64 inter-class variance argmax
// (val_sum[t] == t*cnt[t] exactly, so only the count histogram is needed).
// ---------------------------------------------------------------------------
__device__ __forceinline__ int otsu_scan64(const unsigned* cnt, int lane) {
    uint4 c4 = ((const uint4*)cnt)[lane];
    unsigned cs[4] = {c4.x, c4.y, c4.z, c4.w};

    unsigned long long lc[4], lv[4];
    unsigned long long ccum = 0ull, vcum = 0ull;
#pragma unroll
    for (int k = 0; k < 4; ++k) {
        ccum += cs[k];
        vcum += (unsigned long long)cs[k] * (unsigned)(4 * lane + k);
        lc[k] = ccum;
        lv[k] = vcum;
    }
    unsigned long long cscan = ccum, vscan = vcum;
    for (int d = 1; d < 64; d <<= 1) {
        unsigned long long cu = __shfl_up(cscan, d);
        unsigned long long vu = __shfl_up(vscan, d);
        if (lane >= d) { cscan += cu; vscan += vu; }
    }
    const unsigned long long cbase = cscan - ccum;
    const unsigned long long vbase = vscan - vcum;
    const unsigned long long vtotal = __shfl(vscan, 63);

    double best = -1.0;
    int bestt = 255;
    const double hw = (double)HW_TOTAL;
    const double vtot_d = (double)vtotal;
#pragma unroll
    for (int k = 0; k < 4; ++k) {
        int tt = 4 * lane + k;
        if (tt > 254) continue;
        double nb = (double)(cbase + lc[k]);
        double sb = (double)(vbase + lv[k]);
        double nw = hw - nb;
        double sw = vtot_d - sb;
        double dm = sb / nb - sw / nw;
        double var = nb * nw * dm * dm;
        if (var > best || (var == best && tt < bestt)) { best = var; bestt = tt; }
    }
    for (int d = 32; d >= 1; d >>= 1) {
        double ov = __shfl_xor(best, d);
        int ot = __shfl_xor(bestt, d);
        if (ov > best || (ov == best && ot < bestt)) { best = ov; bestt = ot; }
    }
    return bestt;
}

// ---------------------------------------------------------------------------
// Kernel 1 (unchanged from R15): histogram + pack. 16 LDS sub-hists
// h[sub*256+bin]. While pixels are in registers, pack 4 px -> u32 and store
// the byte image (16 MB, cached; bin re-reads it instead of the 64 MB img).
// Flush: one u16 partial row per block. MODE 1: u32 atomic fallback.
// ---------------------------------------------------------------------------
template <int MODE>
__global__ __launch_bounds__(BLK, 8) void otsu_hist_k(const int4* __restrict__ img4,
                                                      unsigned short* __restrict__ pout,
                                                      unsigned* __restrict__ packed,
                                                      unsigned* __restrict__ ghist) {
    __shared__ unsigned h[NSUB * NBINS];    // 16 KiB
    const int t = threadIdx.x;
    for (int i = t; i < NSUB * NBINS; i += BLK) h[i] = 0;
    __syncthreads();

    unsigned* hp = h + ((t & (NSUB - 1)) << 8);
    const int wave = t >> 6, lane = t & 63;
    const int i0 = blockIdx.x * (BLK * HCPT) + wave * (64 * HCPT) + lane;

    int4 v[HCPT];
#pragma unroll
    for (int k = 0; k < HCPT; ++k) v[k] = img4[i0 + k * 64];
#pragma unroll
    for (int k = 0; k < HCPT; ++k) {
        if (MODE == 0) {
            unsigned pb = (unsigned)v[k].x | ((unsigned)v[k].y << 8) |
                          ((unsigned)v[k].z << 16) | ((unsigned)v[k].w << 24);
            packed[i0 + k * 64] = pb;
        }
        atomicAdd(&hp[(unsigned)v[k].x], 1u);
        atomicAdd(&hp[(unsigned)v[k].y], 1u);
        atomicAdd(&hp[(unsigned)v[k].z], 1u);
        atomicAdd(&hp[(unsigned)v[k].w], 1u);
    }
    __syncthreads();

    if (t < NBINS) {
        unsigned s = 0;
#pragma unroll
        for (int ss = 0; ss < NSUB; ++ss) s += h[(ss << 8) | t];
        if (MODE == 0) {
            pout[blockIdx.x * NBINS + t] = (unsigned short)s;
        } else {
            if (s) atomicAdd(&ghist[t], s);
        }
    }
}

// ---------------------------------------------------------------------------
// Kernel 2 (unchanged from R15): threshold. One block; uint4-vectorized
// reduce of the u16 partials (thread (octet,rowgroup) sums 16 rows of its
// 8-bin octet), LDS reduce, wave-0 exact scan + fp64 argmax.
// ---------------------------------------------------------------------------
__global__ __launch_bounds__(BLK) void otsu_thresh_k(const unsigned short* __restrict__ partials,
                                                     int* __restrict__ d_out,
                                                     unsigned* __restrict__ thr_ws) {
    __shared__ unsigned red[32][NBINS];    // 32 KiB
    __shared__ unsigned cnt[NBINS];

    const int t = threadIdx.x;
    const int o = t & 31;                  // bin octet: bins 8o..8o+7
    const int g = t >> 5;                  // rowgroup: rows 16g..16g+15
    const uint4* p4 = (const uint4*)partials;   // 32 uint4 per row

    unsigned a0 = 0, a1 = 0, a2 = 0, a3 = 0, a4 = 0, a5 = 0, a6 = 0, a7 = 0;
    uint4 q[16];
#pragma unroll
    for (int j = 0; j < 16; ++j) q[j] = p4[(g * 16 + j) * 32 + o];
#pragma unroll
    for (int j = 0; j < 16; ++j) {
        a0 += q[j].x & 0xFFFFu; a1 += q[j].x >> 16;
        a2 += q[j].y & 0xFFFFu; a3 += q[j].y >> 16;
        a4 += q[j].z & 0xFFFFu; a5 += q[j].z >> 16;
        a6 += q[j].w & 0xFFFFu; a7 += q[j].w >> 16;
    }
    red[g][8 * o + 0] = a0; red[g][8 * o + 1] = a1;
    red[g][8 * o + 2] = a2; red[g][8 * o + 3] = a3;
    red[g][8 * o + 4] = a4; red[g][8 * o + 5] = a5;
    red[g][8 * o + 6] = a6; red[g][8 * o + 7] = a7;
    __syncthreads();

    if (t < NBINS) {
        unsigned s = 0;
#pragma unroll
        for (int gg = 0; gg < 32; ++gg) s += red[gg][t];
        cnt[t] = s;
    }
    __syncthreads();

    if (t < 64) {
        int bt = otsu_scan64(cnt, t);
        if (t == 0) {
            d_out[0] = bt;
            *thr_ws = (unsigned)bt;
        }
    }
}

// ---------------------------------------------------------------------------
// Kernel 3: binarize from the packed byte image — coalesced stores AND
// batched loads. R15's loop exposed L2 load latency every iteration
// (VGPR_Count=12 -> no batching); now all 8 u32 chunk-loads issue first
// (8 in flight), then the shfl/compare/store pass. One u32 chunk (4 px) per
// thread per round: wave reads 256 B contiguous (L2/L3-hit), writes 1 KiB
// contiguous nt-store. out4[c] = bin of px {4c-1, 4c, 4c+1, 4c+2}; px 4c-1
// is the top byte of packed[c-1] = prev lane's chunk via shfl_up (lane 0:
// one scalar load). Chunk 0 writes out[0] = thresh.
// ---------------------------------------------------------------------------
__global__ __launch_bounds__(BLK, 8) void otsu_bin_k(const unsigned* __restrict__ packed,
                                                     int* __restrict__ out,
                                                     const unsigned* __restrict__ thr_ws) {
    const int thresh = (int)*thr_ws;       // uniform
    const int t = threadIdx.x;
    const int wave = t >> 6, lane = t & 63;
    const int i0 = blockIdx.x * (BLK * BBATCH) + wave * (64 * BBATCH) + lane;
    int4n* out4 = (int4n*)out;

    unsigned P[BBATCH];
#pragma unroll
    for (int k = 0; k < BBATCH; ++k) P[k] = packed[i0 + k * 64];

#pragma unroll
    for (int k = 0; k < BBATCH; ++k) {
        const int c = i0 + k * 64;                 // u32 chunk: px 4c..4c+3
        unsigned pw = __shfl_up(P[k], 1);          // prev lane's chunk
        if (lane == 0) pw = (c > 0) ? packed[c - 1] : 0u;

        int4n o;
        o.x = ((int)(pw >> 24) <= thresh) ? 0 : 256;            // px 4c-1
        o.y = ((int)(P[k] & 0xFFu) <= thresh) ? 0 : 256;        // px 4c
        o.z = ((int)((P[k] >> 8) & 0xFFu) <= thresh) ? 0 : 256; // px 4c+1
        o.w = ((int)((P[k] >> 16) & 0xFFu) <= thresh) ? 0 : 256;// px 4c+2
        if (c == 0) o.x = thresh;                  // out[0] = threshold
        __builtin_nontemporal_store(o, out4 + c);
    }
    if (i0 == 0)
        out[HW_TOTAL] = ((int)(packed[NCHUNK - 1] >> 24) <= thresh) ? 0 : 256;
}

// ---------------------------------------------------------------------------
// Fallback bin (ws too small): direct img read, ghist scan in prologue.
// ---------------------------------------------------------------------------
__global__ __launch_bounds__(BLK, 8) void otsu_bin_fb_k(const int* __restrict__ img,
                                                        int* __restrict__ out,
                                                        const unsigned* __restrict__ ghist) {
    __shared__ unsigned cnt[NBINS];
    __shared__ int s_thresh;
    const int t = threadIdx.x;
    if (t < NBINS) cnt[t] = ghist[t];
    __syncthreads();
    if (t < 64) {
        int bt = otsu_scan64(cnt, t);
        if (t == 0) s_thresh = bt;
    }
    __syncthreads();
    const int thresh = s_thresh;

    const int wave = t >> 6, lane = t & 63;
    const int i0 = blockIdx.x * (BLK * 8) + wave * (64 * 8) + lane;
#pragma unroll
    for (int k = 0; k < 8; ++k) {
        const int c = i0 + k * 64;
        int4a v = *(const int4a*)(img + (c ? 4 * c - 1 : 0));
        int4n o;
        o.x = (v.x <= thresh) ? 0 : 256;
        o.y = (v.y <= thresh) ? 0 : 256;
        o.z = (v.z <= thresh) ? 0 : 256;
        o.w = (v.w <= thresh) ? 0 : 256;
        if (c == 0) { o.w = o.z; o.z = o.y; o.y = o.x; o.x = thresh; }
        __builtin_nontemporal_store(o, (int4n*)out + c);
    }
    if (i0 == 0)
        out[HW_TOTAL] = (img[HW_TOTAL - 1] <= thresh) ? 0 : 256;
}

extern "C" void kernel_launch(void* const* d_in, const int* in_sizes, int n_in,
                              void* d_out, int out_size, void* d_ws, size_t ws_size,
                              hipStream_t stream) {
    const int* img = (const int*)d_in[0];
    int* out = (int*)d_out;
    unsigned* thr_ws = (unsigned*)d_ws;
    unsigned short* part16 = (unsigned short*)((char*)d_ws + WS_PART_OFF);
    unsigned* packed = (unsigned*)((char*)d_ws + WS_PACK_OFF);
    unsigned* ghist = (unsigned*)((char*)d_ws + WS_PART_OFF);

    if (ws_size >= (size_t)WS_NEED) {
        // 3-node path: hist+pack -> thresh -> bin(packed). No atomics/memsets.
        otsu_hist_k<0><<<HGRID, BLK, 0, stream>>>((const int4*)img, part16, packed, nullptr);
        otsu_thresh_k<<<1, BLK, 0, stream>>>(part16, out, thr_ws);
        otsu_bin_k<<<BGRID, BLK, 0, stream>>>(packed, out, thr_ws);
    } else {
        // fallback: atomic flush into a single u32 256-bin histogram
        (void)hipMemsetAsync(ghist, 0, NBINS * sizeof(unsigned), stream);
        otsu_hist_k<1><<<HGRID, BLK, 0, stream>>>((const int4*)img, nullptr, nullptr, ghist);
        otsu_bin_fb_k<<<BGRID, BLK, 0, stream>>>(img, out, ghist);
    }
}